// Round 1
// baseline (94.335 us; speedup 1.0000x reference)
//
#include <hip/hip_runtime.h>

#define L 1024
#define C 16
#define RT 256          // rows of M per block tile
#define JT 32           // j (columns) per LDS tile
#define MSTRIDE (JT + 4) // pad 4 floats: keeps 16B alignment, breaks bank aliasing

__device__ __forceinline__ int lower_bound_i(const int* __restrict__ a, int n, int key) {
  int lo = 0, hi = n;
  while (lo < hi) {
    int mid = (lo + hi) >> 1;
    if (a[mid] < key) lo = mid + 1; else hi = mid;
  }
  return lo;
}

__global__ __launch_bounds__(256, 4) void mp_kernel(
    const float* __restrict__ x,
    const float* __restrict__ M,
    const int*   __restrict__ batch,
    float*       __restrict__ out,
    int n_nodes)
{
  __shared__ float Mt[RT * MSTRIDE];  // 36 KB
  __shared__ float Xs[JT * C];        // 2 KB

  const int b  = blockIdx.y;
  // coeffs_batch is sorted: per-block binary search for this graph's range.
  const int sb = lower_bound_i(batch, n_nodes, b);
  const int se = lower_bound_i(batch, n_nodes, b + 1);
  int cnt = se - sb;
  if (cnt > L) cnt = L;
  const int r0 = blockIdx.x * RT;
  if (r0 >= cnt) return;            // uniform per block

  const float* Mb = M + (size_t)b * L * L;
  const int t  = threadIdx.x;
  const int cg = t & 1;             // channel group: 0 -> c[0..7], 1 -> c[8..15]
  const int rl = t >> 1;            // 0..127; thread handles rows rl and rl+128
  const int c0 = cg * 8;

  float acc0[8] = {0.f,0.f,0.f,0.f,0.f,0.f,0.f,0.f};
  float acc1[8] = {0.f,0.f,0.f,0.f,0.f,0.f,0.f,0.f};

  const int njt = (cnt + JT - 1) / JT;
  for (int jt = 0; jt < njt; ++jt) {
    const int j0 = jt * JT;
    __syncthreads();
    // ---- stage M tile: rows r0..r0+255, cols j0..j0+31 (row-guarded: no HBM
    // fetch beyond cnt; stale LDS there feeds rows we never write) ----
    #pragma unroll
    for (int p = 0; p < 8; ++p) {
      int idx = p * 256 + t;
      int row = idx >> 3;
      int cs  = (idx & 7) << 2;
      int gr  = r0 + row;
      if (gr < cnt) {
        float4 v = *reinterpret_cast<const float4*>(Mb + (size_t)gr * L + j0 + cs);
        *reinterpret_cast<float4*>(&Mt[row * MSTRIDE + cs]) = v;
      }
    }
    // ---- stage X tile: 32 nodes x 16 ch, zero-filled past cnt so dead M
    // columns contribute exactly 0 ----
    if (t < (JT * C / 4)) {
      int j  = t >> 2;
      int cs = (t & 3) << 2;
      float4 v = make_float4(0.f, 0.f, 0.f, 0.f);
      if (j0 + j < cnt)
        v = *reinterpret_cast<const float4*>(x + (size_t)(sb + j0 + j) * C + cs);
      *reinterpret_cast<float4*>(&Xs[j * C + cs]) = v;
    }
    __syncthreads();
    // ---- compute: per thread 2 rows x 8 channels ----
    #pragma unroll
    for (int j4 = 0; j4 < JT / 4; ++j4) {
      float4 ma = *reinterpret_cast<const float4*>(&Mt[rl * MSTRIDE + (j4 << 2)]);
      float4 mb = *reinterpret_cast<const float4*>(&Mt[(rl + 128) * MSTRIDE + (j4 << 2)]);
      #pragma unroll
      for (int jj = 0; jj < 4; ++jj) {
        const int j = (j4 << 2) + jj;
        float4 xlo = *reinterpret_cast<const float4*>(&Xs[j * C + c0]);
        float4 xhi = *reinterpret_cast<const float4*>(&Xs[j * C + c0 + 4]);
        float mja = (jj == 0) ? ma.x : (jj == 1) ? ma.y : (jj == 2) ? ma.z : ma.w;
        float mjb = (jj == 0) ? mb.x : (jj == 1) ? mb.y : (jj == 2) ? mb.z : mb.w;
        acc0[0] += mja * xlo.x; acc0[1] += mja * xlo.y;
        acc0[2] += mja * xlo.z; acc0[3] += mja * xlo.w;
        acc0[4] += mja * xhi.x; acc0[5] += mja * xhi.y;
        acc0[6] += mja * xhi.z; acc0[7] += mja * xhi.w;
        acc1[0] += mjb * xlo.x; acc1[1] += mjb * xlo.y;
        acc1[2] += mjb * xlo.z; acc1[3] += mjb * xlo.w;
        acc1[4] += mjb * xhi.x; acc1[5] += mjb * xhi.y;
        acc1[6] += mjb * xhi.z; acc1[7] += mjb * xhi.w;
      }
    }
  }
  // ---- epilogue: out[i, c] in original node order (i = sb + pos) ----
  int ra = r0 + rl;
  if (ra < cnt) {
    float* o = out + (size_t)(sb + ra) * C + c0;
    *reinterpret_cast<float4*>(o)     = make_float4(acc0[0], acc0[1], acc0[2], acc0[3]);
    *reinterpret_cast<float4*>(o + 4) = make_float4(acc0[4], acc0[5], acc0[6], acc0[7]);
  }
  int rb = r0 + rl + 128;
  if (rb < cnt) {
    float* o = out + (size_t)(sb + rb) * C + c0;
    *reinterpret_cast<float4*>(o)     = make_float4(acc1[0], acc1[1], acc1[2], acc1[3]);
    *reinterpret_cast<float4*>(o + 4) = make_float4(acc1[4], acc1[5], acc1[6], acc1[7]);
  }
}

extern "C" void kernel_launch(void* const* d_in, const int* in_sizes, int n_in,
                              void* d_out, int out_size, void* d_ws, size_t ws_size,
                              hipStream_t stream) {
  const float* x     = (const float*)d_in[0];
  const float* M     = (const float*)d_in[1];
  const int*   batch = (const int*)d_in[2];
  float*       out   = (float*)d_out;
  const int n_nodes  = in_sizes[2];           // N = 65536
  const int B        = in_sizes[1] / (L * L); // 128
  dim3 grid(L / RT, B);
  mp_kernel<<<grid, dim3(256), 0, stream>>>(x, M, batch, out, n_nodes);
}